// Round 10
// baseline (122.728 us; speedup 1.0000x reference)
//
#include <hip/hip_runtime.h>

#define BATCH 4
#define CTX   2048
#define EMB   1024
#define HEAD  128

typedef __attribute__((ext_vector_type(8))) short bf16x8;
typedef __attribute__((ext_vector_type(4))) float f32x4;
typedef const __attribute__((address_space(1))) unsigned int* gas_t;
typedef __attribute__((address_space(3))) unsigned int* las_t;

#define FINF (__builtin_inff())
__device__ inline float fexp2(float x) { return __builtin_amdgcn_exp2f(x); }

// async global->LDS, 16B per lane. LDS dest = wave-uniform base + lane*16.
__device__ inline void cp16(const void* g, void* l) {
    __builtin_amdgcn_global_load_lds((gas_t)g, (las_t)l, 16, 0, 0);
}

__device__ inline unsigned short f2bf(float f) {
    union { float f; unsigned u; } v; v.f = f;
    unsigned r = v.u + 0x7fffu + ((v.u >> 16) & 1u);
    return (unsigned short)(r >> 16);
}
__device__ inline unsigned pk2(float a, float b) {
    return (unsigned)f2bf(a) | ((unsigned)f2bf(b) << 16);
}
__device__ inline float bf2f(unsigned u16) {
    union { unsigned u; float f; } v; v.u = u16 << 16; return v.f;
}

// ---------------------------------------------------------------------------
// W[1024][128] fp32 -> Wt[w][128][1024] bf16 (transposed). grid (16,2,3).
// ---------------------------------------------------------------------------
__global__ __launch_bounds__(256)
void transpose_w_kernel(const float* __restrict__ Wq, const float* __restrict__ Wk,
                        const float* __restrict__ Wv, unsigned short* __restrict__ Wt) {
    const int k0 = blockIdx.x * 64;
    const int h0 = blockIdx.y * 64;
    const int w  = blockIdx.z;
    const float* W = (w == 0) ? Wq : (w == 1) ? Wk : Wv;
    __shared__ float Ts[64][65];
    const int tid = threadIdx.x;
    #pragma unroll
    for (int it = 0; it < 4; ++it) {
        const int kk = (tid >> 4) + it * 16;
        const int c4 = (tid & 15) * 4;
        const float4 f = *(const float4*)&W[(size_t)(k0 + kk) * HEAD + h0 + c4];
        Ts[kk][c4 + 0] = f.x; Ts[kk][c4 + 1] = f.y;
        Ts[kk][c4 + 2] = f.z; Ts[kk][c4 + 3] = f.w;
    }
    __syncthreads();
    const int hr  = tid >> 2;
    const int kc0 = (tid & 3) * 16;
    union { unsigned short s[16]; uint4 q[2]; } tmp;
    #pragma unroll
    for (int i = 0; i < 16; ++i) tmp.s[i] = f2bf(Ts[kc0 + i][hr]);
    unsigned short* dst = &Wt[(size_t)w * HEAD * EMB + (size_t)(h0 + hr) * EMB + k0 + kc0];
    ((uint4*)dst)[0] = tmp.q[0];
    ((uint4*)dst)[1] = tmp.q[1];
}

// ---------------------------------------------------------------------------
// QKV projection v4: single-wave blocks, BK=64 (16 steps, 32 MFMA/step) so
// the step body (~650 cyc: 24 ds_read_b128 + 32 MFMA + pack) covers the
// one-step-ahead global_load_lds latency (R9's BK=32 body ~300 cyc left
// ~600 cyc exposed every step). No barriers (wave-coherent LDS), waitcnt(0).
// All wsel use swapped operands: C[m=h][n=token] -> q/k epilogues are 16
// packed uint2 stores (R9: 64 scalar 2B stores). grid (256,3), 48KB LDS,
// 3 blocks/CU.
// ---------------------------------------------------------------------------
__global__ __launch_bounds__(64, 1)
void proj_kernel(const float* __restrict__ x, const unsigned short* __restrict__ Wt,
                 unsigned short* __restrict__ qb, unsigned short* __restrict__ kb,
                 unsigned short* __restrict__ vt) {
    __shared__ __align__(16) char smem[49152];
    char* Ab = smem;            // 2 x 8KB  : x tile [32 tok][64 k] fp32, 256B rows
    char* Bb = smem + 16384;    // 2 x 16KB : W tile [128 h][64 k] bf16, 128B rows

    const int wsel = blockIdx.y;
    const int lane = threadIdx.x;
    const int p = lane >> 4, c = lane & 15;
    const int m0 = blockIdx.x * 32;
    const unsigned short* Wp = Wt + (size_t)wsel * HEAD * EMB;

    const int uA = c;        // A-row swizzle key: row r = n2*16+c -> r&15 = c
    const int uB = c & 7;    // B-row swizzle key: row h = nt*16+c -> h&7 = c&7

    // swizzle applied on the GLOBAL side (LDS dest must stay lane-linear)
    auto stage = [&](int bi, int ks) {
        #pragma unroll
        for (int i = 0; i < 8; ++i) {      // A: 32 rows x 256B = 8KB
            const int f = i * 64 + lane;
            const int r = f >> 4, s = f & 15, q = s ^ (r & 15);
            cp16(&x[(size_t)(m0 + r) * EMB + ks * 64 + q * 4],
                 Ab + bi * 8192 + i * 1024);
        }
        #pragma unroll
        for (int i = 0; i < 16; ++i) {     // B: 128 rows x 128B = 16KB
            const int f = i * 64 + lane;
            const int h = f >> 3, s = f & 7, q = s ^ (h & 7);
            cp16(&Wp[(size_t)h * EMB + ks * 64 + q * 8],
                 Bb + bi * 16384 + i * 1024);
        }
    };
    // x row r, k-chunk kc (32 k): two swizzled 16B slots -> packed bf16x8
    auto xfrag = [&](const char* Ac, int r, int kc) {
        const int g0 = kc * 8 + 2 * p;
        const float4 a0 = *(const float4*)(Ac + r * 256 + ((g0 ^ uA) * 16));
        const float4 a1 = *(const float4*)(Ac + r * 256 + (((g0 + 1) ^ uA) * 16));
        union { unsigned u[4]; bf16x8 v; } xf;
        xf.u[0] = pk2(a0.x, a0.y); xf.u[1] = pk2(a0.z, a0.w);
        xf.u[2] = pk2(a1.x, a1.y); xf.u[3] = pk2(a1.z, a1.w);
        return xf.v;
    };

    f32x4 acc[2][8];                       // [n2 = token-tile][mt = h-tile]
    #pragma unroll
    for (int i = 0; i < 2; ++i)
        #pragma unroll
        for (int j = 0; j < 8; ++j) acc[i][j] = (f32x4){0.f, 0.f, 0.f, 0.f};

    stage(0, 0);
    for (int ks = 0; ks < 16; ++ks) {
        const int cur = ks & 1;
        __builtin_amdgcn_s_waitcnt(0);     // drain stage(ks), issued one step ago
        const char* Ac = Ab + cur * 8192;
        const char* Bc = Bb + cur * 16384;
        bf16x8 xv[2][2], wf[8][2];
        #pragma unroll
        for (int n2 = 0; n2 < 2; ++n2)
            #pragma unroll
            for (int kc = 0; kc < 2; ++kc)
                xv[n2][kc] = xfrag(Ac, n2 * 16 + c, kc);
        #pragma unroll
        for (int nt = 0; nt < 8; ++nt) {
            const int h = nt * 16 + c;
            #pragma unroll
            for (int kc = 0; kc < 2; ++kc)
                wf[nt][kc] = *(const bf16x8*)(Bc + h * 128 + (((kc * 4 + p) ^ uB) * 16));
        }
        if (ks + 1 < 16) stage(cur ^ 1, ks + 1);   // prefetch under this step's MFMAs
        #pragma unroll
        for (int kc = 0; kc < 2; ++kc)
            #pragma unroll
            for (int mt = 0; mt < 8; ++mt) {
                acc[0][mt] = __builtin_amdgcn_mfma_f32_16x16x32_bf16(wf[mt][kc], xv[0][kc], acc[0][mt], 0, 0, 0);
                acc[1][mt] = __builtin_amdgcn_mfma_f32_16x16x32_bf16(wf[mt][kc], xv[1][kc], acc[1][mt], 0, 0, 0);
            }
    }

    // C[m = h = mt*16 + p*4 + rr][n = token = m0 + n2*16 + c]
    if (wsel < 2) {
        unsigned short* outp = (wsel == 0) ? qb : kb;
        #pragma unroll
        for (int n2 = 0; n2 < 2; ++n2) {
            const int token = m0 + n2 * 16 + c;
            #pragma unroll
            for (int mt = 0; mt < 8; ++mt) {
                union { unsigned short sh[4]; uint2 u; } t;
                #pragma unroll
                for (int rr = 0; rr < 4; ++rr) t.sh[rr] = f2bf(acc[n2][mt][rr]);
                *(uint2*)&outp[(size_t)token * HEAD + mt * 16 + p * 4] = t.u;
            }
        }
    } else {
        const int bidx = m0 >> 11;
        const int tl   = m0 & (CTX - 1);
        unsigned short* vbp = vt + (size_t)bidx * HEAD * CTX;
        #pragma unroll
        for (int mt = 0; mt < 8; ++mt)
            #pragma unroll
            for (int rr = 0; rr < 4; ++rr) {
                const int h = mt * 16 + p * 4 + rr;
                #pragma unroll
                for (int n2 = 0; n2 < 2; ++n2)
                    vbp[(size_t)h * CTX + tl + n2 * 16 + c] = f2bf(acc[n2][mt][rr]);
            }
    }
}

// ---------------------------------------------------------------------------
// Split-KV flash attention (R7 v1 — proven fastest). Block = 256 threads
// (4 waves) = 64 q rows, one 512-kv chunk (<=8 steps of 64). K/V staged via
// global_load_lds, double-buffered (64KB LDS). grid (80, 4).
// ---------------------------------------------------------------------------
__global__ __launch_bounds__(256, 2)
void attn_split_kernel(const unsigned short* __restrict__ qb,
                       const unsigned short* __restrict__ kb,
                       const unsigned short* __restrict__ vt,
                       unsigned short* __restrict__ pO,
                       float* __restrict__ pM, float* __restrict__ pL) {
    __shared__ __align__(16) char smem[65536];
    char* Kb = smem;            // 2 x 16KB : [64 kv][128 h] bf16
    char* Vb = smem + 32768;    // 2 x 16KB : [128 h][64 kv] bf16

    const int g = blockIdx.x;   // 0..79
    const int b = blockIdx.y;
    int T, ch;
    if (g < 8)       { T = g;                ch = 0; }
    else if (g < 24) { T = 8  + ((g - 8) >> 1);  ch = (g - 8) & 1; }
    else if (g < 48) { T = 16 + (g - 24) / 3;    ch = (g - 24) % 3; }
    else             { T = 24 + ((g - 48) >> 2); ch = (g - 48) & 3; }
    const int nch    = (T >> 3) + 1;
    const int kstart = ch * 512;
    const int kend   = min(kstart + 512, 64 * (T + 1));
    const int nsteps = (kend - kstart) >> 6;
    const bool lastchunk = (ch == nch - 1);

    const int tid  = threadIdx.x;
    const int wv   = tid >> 6;
    const int lane = tid & 63;
    const int p = lane >> 4, c = lane & 15;
    const int t0 = T * 64;
    const int qg = t0 + wv * 16 + c;
    const int u7 = c & 7;

    const unsigned short* kbat = kb + (size_t)b * CTX * HEAD;
    const unsigned short* vbat = vt + (size_t)b * HEAD * CTX;

    bf16x8 qf[4];
    #pragma unroll
    for (int ks = 0; ks < 4; ++ks)
        qf[ks] = *(const bf16x8*)&qb[((size_t)b * CTX + t0 + wv * 16 + c) * HEAD + ks * 32 + p * 8];

    f32x4 o[8];
    #pragma unroll
    for (int i = 0; i < 8; ++i) o[i] = (f32x4){0.f, 0.f, 0.f, 0.f};
    float m = -FINF, l = 0.f;

    const int  slA = 32 * (p & 1) + c;
    const int  slB = slA + 16;
    const bool thi = (p >> 1) != 0;
    const float scale2 = 0.08838834764831845f * 1.44269504088896340f;  // 1/sqrt(128)*log2e

    auto stage = [&](int bi, int js) {
        const unsigned short* kg = kbat + (size_t)(kstart + js * 64) * HEAD;
        #pragma unroll
        for (int i = 0; i < 4; ++i) {      // K: 64 rows x 256B
            const int f = i * 256 + tid;
            const int r = f >> 4, s = f & 15, q = s ^ (r & 7);
            cp16(kg + (size_t)r * HEAD + q * 8, Kb + bi * 16384 + (f >> 6) * 1024);
        }
        const unsigned short* vg = vbat + kstart + js * 64;
        #pragma unroll
        for (int i = 0; i < 4; ++i) {      // V: 128 rows x 128B
            const int f = i * 256 + tid;
            const int r = f >> 3, s = f & 7, q = s ^ (r & 7);
            cp16(vg + (size_t)r * CTX + q * 8, Vb + bi * 16384 + (f >> 6) * 1024);
        }
    };

    stage(0, 0);
    for (int js = 0; js < nsteps; ++js) {
        const int cur = js & 1;
        __builtin_amdgcn_s_waitcnt(0);
        __syncthreads();                   // buf[cur] staged by all waves

        bf16x8 kfr[4][4];
        #pragma unroll
        for (int nt = 0; nt < 4; ++nt) {
            const char* rp = Kb + cur * 16384 + (nt * 16 + c) * 256;
            #pragma unroll
            for (int ks = 0; ks < 4; ++ks)
                kfr[nt][ks] = *(const bf16x8*)(rp + (((ks * 4 + p) ^ u7) * 16));
        }
        if (js + 1 < nsteps) stage(cur ^ 1, js + 1);

        f32x4 st[4];
        #pragma unroll
        for (int nt = 0; nt < 4; ++nt) st[nt] = (f32x4){0.f, 0.f, 0.f, 0.f};
        #pragma unroll
        for (int ks = 0; ks < 4; ++ks)
            #pragma unroll
            for (int nt = 0; nt < 4; ++nt)
                st[nt] = __builtin_amdgcn_mfma_f32_16x16x32_bf16(kfr[nt][ks], qf[ks], st[nt], 0, 0, 0);

        bf16x8 vfr[2][8];
        #pragma unroll
        for (int mt = 0; mt < 8; ++mt) {
            const char* rp = Vb + cur * 16384 + (mt * 16 + c) * 128;
            #pragma unroll
            for (int ch2 = 0; ch2 < 2; ++ch2)
                vfr[ch2][mt] = *(const bf16x8*)(rp + (((ch2 * 4 + p) ^ u7) * 16));
        }

        float s[4][4];
        float lm = -FINF;
        if (lastchunk && js == nsteps - 1) {
            #pragma unroll
            for (int nt = 0; nt < 4; ++nt)
                #pragma unroll
                for (int r = 0; r < 4; ++r) {
                    const int kv = kstart + js * 64 + nt * 16 + p * 4 + r;
                    float v = st[nt][r] * scale2;
                    v = (kv <= qg) ? v : -FINF;
                    s[nt][r] = v;
                    lm = fmaxf(lm, v);
                }
        } else {
            #pragma unroll
            for (int nt = 0; nt < 4; ++nt)
                #pragma unroll
                for (int r = 0; r < 4; ++r) {
                    const float v = st[nt][r] * scale2;
                    s[nt][r] = v;
                    lm = fmaxf(lm, v);
                }
        }
        lm = fmaxf(lm, __shfl_xor(lm, 16, 64));
        lm = fmaxf(lm, __shfl_xor(lm, 32, 64));
        const float m_new = fmaxf(m, lm);
        const float alpha = fexp2(m - m_new);
        float ls = 0.f;
        #pragma unroll
        for (int nt = 0; nt < 4; ++nt)
            #pragma unroll
            for (int r = 0; r < 4; ++r) {
                const float pv = fexp2(s[nt][r] - m_new);
                s[nt][r] = pv;
                ls += pv;
            }
        ls += __shfl_xor(ls, 16, 64);
        ls += __shfl_xor(ls, 32, 64);
        l = l * alpha + ls;
        m = m_new;
        #pragma unroll
        for (int i = 0; i < 8; ++i) {
            o[i][0] *= alpha; o[i][1] *= alpha;
            o[i][2] *= alpha; o[i][3] *= alpha;
        }
        #pragma unroll
        for (int ch2 = 0; ch2 < 2; ++ch2) {
            const unsigned pa0 = pk2(s[2*ch2][0],     s[2*ch2][1]);
            const unsigned pb0 = pk2(s[2*ch2][2],     s[2*ch2][3]);
            const unsigned pa1 = pk2(s[2*ch2 + 1][0], s[2*ch2 + 1][1]);
            const unsigned pb1 = pk2(s[2*ch2 + 1][2], s[2*ch2 + 1][3]);
            const unsigned u0a = __shfl((int)pa0, slA, 64), u0b = __shfl((int)pa1, slA, 64);
            const unsigned u1a = __shfl((int)pb0, slA, 64), u1b = __shfl((int)pb1, slA, 64);
            const unsigned u2a = __shfl((int)pa0, slB, 64), u2b = __shfl((int)pa1, slB, 64);
            const unsigned u3a = __shfl((int)pb0, slB, 64), u3b = __shfl((int)pb1, slB, 64);
            union { unsigned u[4]; bf16x8 v; } pf;
            pf.u[0] = thi ? u0b : u0a;
            pf.u[1] = thi ? u1b : u1a;
            pf.u[2] = thi ? u2b : u2a;
            pf.u[3] = thi ? u3b : u3a;
            #pragma unroll
            for (int mt = 0; mt < 8; ++mt)
                o[mt] = __builtin_amdgcn_mfma_f32_16x16x32_bf16(vfr[ch2][mt], pf.v, o[mt], 0, 0, 0);
        }
    }

    const size_t pbase = (size_t)(b * 32 + T) * 4 + ch;
    unsigned short* po = pO + pbase * (64 * 128) + (wv * 16 + c) * 128;
    #pragma unroll
    for (int mt = 0; mt < 8; ++mt) {
        union { unsigned short sh[4]; uint2 u; } t;
        #pragma unroll
        for (int r = 0; r < 4; ++r) t.sh[r] = f2bf(o[mt][r]);
        *(uint2*)&po[mt * 16 + p * 4] = t.u;
    }
    if (p == 0) {
        pM[pbase * 64 + wv * 16 + c] = m;
        pL[pbase * 64 + wv * 16 + c] = l;
    }
}

// ---------------------------------------------------------------------------
// Merge up to 4 partial chunks. grid (32, 4), 256 threads.
// ---------------------------------------------------------------------------
__global__ __launch_bounds__(256)
void attn_merge_kernel(const unsigned short* __restrict__ pO,
                       const float* __restrict__ pM, const float* __restrict__ pL,
                       float* __restrict__ out) {
    const int T = blockIdx.x, b = blockIdx.y;
    const int nch = (T >> 3) + 1;
    const int tid = threadIdx.x;
    const int r   = tid >> 2;
    const int c0  = (tid & 3) * 32;
    const size_t base = (size_t)(b * 32 + T) * 4;

    float mv[4], lv[4];
    float M = -FINF;
    #pragma unroll
    for (int i = 0; i < 4; ++i) {
        if (i < nch) { mv[i] = pM[(base + i) * 64 + r]; lv[i] = pL[(base + i) * 64 + r]; }
        else         { mv[i] = -FINF;                   lv[i] = 0.f; }
        M = fmaxf(M, mv[i]);
    }
    float w[4], L = 0.f;
    #pragma unroll
    for (int i = 0; i < 4; ++i) { w[i] = fexp2(mv[i] - M); L += w[i] * lv[i]; }
    const float inv = 1.f / L;

    float acc[32];
    #pragma unroll
    for (int j = 0; j < 32; ++j) acc[j] = 0.f;
    #pragma unroll
    for (int i = 0; i < 4; ++i) {
        if (i < nch) {
            const unsigned* s32 = (const unsigned*)(pO + (base + i) * (64 * 128) + r * 128 + c0);
            const float wi = w[i];
            #pragma unroll
            for (int jw = 0; jw < 16; ++jw) {
                const unsigned u = s32[jw];
                acc[2 * jw]     += wi * bf2f(u & 0xffffu);
                acc[2 * jw + 1] += wi * bf2f(u >> 16);
            }
        }
    }
    float* orow = out + ((size_t)b * CTX + T * 64 + r) * HEAD + c0;
    #pragma unroll
    for (int j4 = 0; j4 < 8; ++j4) {
        float4 ov = make_float4(acc[4*j4] * inv, acc[4*j4+1] * inv,
                                acc[4*j4+2] * inv, acc[4*j4+3] * inv);
        *(float4*)&orow[4 * j4] = ov;
    }
}

// ---------------------------------------------------------------------------
// Fallback attention (R6): single-wave blocks, used if ws too small for split.
// ---------------------------------------------------------------------------
__global__ __launch_bounds__(64, 1)
void attn_kernel(const unsigned short* __restrict__ qb,
                 const unsigned short* __restrict__ kb,
                 const unsigned short* __restrict__ vt,
                 float* __restrict__ out) {
    __shared__ __align__(16) char smem[65536];
    char* Kb = smem;
    char* Vb = smem + 32768;
    const int bx   = blockIdx.x;
    const int b    = bx & 3;
    const int tile = 127 - (bx >> 2);
    const int lane = threadIdx.x;
    const int p = lane >> 4, c = lane & 15;
    const int t0 = tile * 16;
    const int qg = t0 + c;
    const int u7 = c & 7;
    const unsigned short* kbat = kb + (size_t)b * CTX * HEAD;
    const unsigned short* vbat = vt + (size_t)b * HEAD * CTX;
    bf16x8 qf[4];
    #pragma unroll
    for (int ks = 0; ks < 4; ++ks)
        qf[ks] = *(const bf16x8*)&qb[((size_t)b * CTX + t0 + c) * HEAD + ks * 32 + p * 8];
    f32x4 o[8];
    #pragma unroll
    for (int i = 0; i < 8; ++i) o[i] = (f32x4){0.f, 0.f, 0.f, 0.f};
    float m = -FINF, l = 0.f;
    const int  slA = 32 * (p & 1) + c;
    const int  slB = slA + 16;
    const bool thi = (p >> 1) != 0;
    const int  nsteps = (tile + 4) >> 2;
    const float scale2 = 0.08838834764831845f * 1.44269504088896340f;
    auto stage = [&](int bi, int js) {
        const unsigned short* kg = kbat + (size_t)(js * 64) * HEAD;
        #pragma unroll
        for (int i = 0; i < 16; ++i) {
            const int f = i * 64 + lane;
            const int r = f >> 4, s = f & 15, q = s ^ (r & 7);
            cp16(kg + (size_t)r * HEAD + q * 8, Kb + bi * 16384 + i * 1024);
        }
        #pragma unroll
        for (int i = 0; i < 16; ++i) {
            const int f = i * 64 + lane;
            const int r = f >> 3, s = f & 7, q = s ^ (r & 7);
            cp16(vbat + (size_t)r * CTX + js * 64 + q * 8, Vb + bi * 16384 + i * 1024);
        }
    };
    stage(0, 0);
    for (int js = 0; js < nsteps; ++js) {
        const int cur = js & 1;
        __builtin_amdgcn_s_waitcnt(0);
        bf16x8 kfr[4][4], vfr[2][8];
        #pragma unroll
        for (int nt = 0; nt < 4; ++nt) {
            const char* rp = Kb + cur * 16384 + (nt * 16 + c) * 256;
            #pragma unroll
            for (int ks = 0; ks < 4; ++ks)
                kfr[nt][ks] = *(const bf16x8*)(rp + (((ks * 4 + p) ^ u7) * 16));
        }
        #pragma unroll
        for (int mt = 0; mt < 8; ++mt) {
            const char* rp = Vb + cur * 16384 + (mt * 16 + c) * 128;
            #pragma unroll
            for (int ch = 0; ch < 2; ++ch)
                vfr[ch][mt] = *(const bf16x8*)(rp + (((ch * 4 + p) ^ u7) * 16));
        }
        if (js + 1 < nsteps) stage(cur ^ 1, js + 1);
        const int c0 = js * 64;
        f32x4 st[4];
        #pragma unroll
        for (int nt = 0; nt < 4; ++nt) st[nt] = (f32x4){0.f, 0.f, 0.f, 0.f};
        #pragma unroll
        for (int ks = 0; ks < 4; ++ks)
            #pragma unroll
            for (int nt = 0; nt < 4; ++nt)
                st[nt] = __builtin_amdgcn_mfma_f32_16x16x32_bf16(kfr[nt][ks], qf[ks], st[nt], 0, 0, 0);
        float s[4][4];
        float lm = -FINF;
        if (js == nsteps - 1) {
            #pragma unroll
            for (int nt = 0; nt < 4; ++nt)
                #pragma unroll
                for (int r = 0; r < 4; ++r) {
                    const int kv = c0 + nt * 16 + p * 4 + r;
                    float v = st[nt][r] * scale2;
                    v = (kv <= qg) ? v : -FINF;
                    s[nt][r] = v;
                    lm = fmaxf(lm, v);
                }
        } else {
            #pragma unroll
            for (int nt = 0; nt < 4; ++nt)
                #pragma unroll
                for (int r = 0; r < 4; ++r) {
                    const float v = st[nt][r] * scale2;
                    s[nt][r] = v;
                    lm = fmaxf(lm, v);
                }
        }
        lm = fmaxf(lm, __shfl_xor(lm, 16, 64));
        lm = fmaxf(lm, __shfl_xor(lm, 32, 64));
        const float m_new = fmaxf(m, lm);
        const float alpha = fexp2(m - m_new);
        float ls = 0.f;
        #pragma unroll
        for (int nt = 0; nt < 4; ++nt)
            #pragma unroll
            for (int r = 0; r < 4; ++r) {
                const float pv = fexp2(s[nt][r] - m_new);
                s[nt][r] = pv;
                ls += pv;
            }
        ls += __shfl_xor(ls, 16, 64);
        ls += __shfl_xor(ls, 32, 64);
        l = l * alpha + ls;
        m = m_new;
        #pragma unroll
        for (int i = 0; i < 8; ++i) {
            o[i][0] *= alpha; o[i][1] *= alpha;
            o[i][2] *= alpha; o[i][3] *= alpha;
        }
        #pragma unroll
        for (int ch = 0; ch < 2; ++ch) {
            const unsigned pa0 = pk2(s[2*ch][0],     s[2*ch][1]);
            const unsigned pb0 = pk2(s[2*ch][2],     s[2*ch][3]);
            const unsigned pa1 = pk2(s[2*ch + 1][0], s[2*ch + 1][1]);
            const unsigned pb1 = pk2(s[2*ch + 1][2], s[2*ch + 1][3]);
            const unsigned u0a = __shfl((int)pa0, slA, 64), u0b = __shfl((int)pa1, slA, 64);
            const unsigned u1a = __shfl((int)pb0, slA, 64), u1b = __shfl((int)pb1, slA, 64);
            const unsigned u2a = __shfl((int)pa0, slB, 64), u2b = __shfl((int)pa1, slB, 64);
            const unsigned u3a = __shfl((int)pb0, slB, 64), u3b = __shfl((int)pb1, slB, 64);
            union { unsigned u[4]; bf16x8 v; } pf;
            pf.u[0] = thi ? u0b : u0a;
            pf.u[1] = thi ? u1b : u1a;
            pf.u[2] = thi ? u2b : u2a;
            pf.u[3] = thi ? u3b : u3a;
            #pragma unroll
            for (int mt = 0; mt < 8; ++mt)
                o[mt] = __builtin_amdgcn_mfma_f32_16x16x32_bf16(vfr[ch][mt], pf.v, o[mt], 0, 0, 0);
        }
    }
    const float linv = 1.f / l;
    float* orow = out + ((size_t)b * CTX + t0 + c) * HEAD;
    #pragma unroll
    for (int mt = 0; mt < 8; ++mt) {
        float4 ov = make_float4(o[mt][0] * linv, o[mt][1] * linv,
                                o[mt][2] * linv, o[mt][3] * linv);
        *(float4*)&orow[mt * 16 + p * 4] = ov;
    }
}

// ---------------------------------------------------------------------------
extern "C" void kernel_launch(void* const* d_in, const int* in_sizes, int n_in,
                              void* d_out, int out_size, void* d_ws, size_t ws_size,
                              hipStream_t stream) {
    const float* x  = (const float*)d_in[0];
    const float* Wq = (const float*)d_in[1];
    const float* Wk = (const float*)d_in[2];
    const float* Wv = (const float*)d_in[3];
    float* out = (float*)d_out;

    unsigned short* Wt = (unsigned short*)d_ws;                 // 3*128*1024
    unsigned short* qb = Wt + (size_t)3 * HEAD * EMB;           // 8192*128
    unsigned short* kb = qb + (size_t)BATCH * CTX * HEAD;
    unsigned short* vt = kb + (size_t)BATCH * CTX * HEAD;
    unsigned short* pO = vt + (size_t)BATCH * CTX * HEAD;       // 4*32*4*64*128 bf16
    float* pM = (float*)(pO + (size_t)BATCH * 32 * 4 * 64 * 128);
    float* pL = pM + (size_t)BATCH * 32 * 4 * 64;

    const size_t need = (size_t)((char*)(pL + BATCH * 32 * 4 * 64) - (char*)d_ws);

    transpose_w_kernel<<<dim3(16, 2, 3), 256, 0, stream>>>(Wq, Wk, Wv, Wt);
    proj_kernel<<<dim3((BATCH * CTX) / 32, 3), 64, 0, stream>>>(x, Wt, qb, kb, vt);
    if (ws_size >= need) {
        attn_split_kernel<<<dim3(80, 4), 256, 0, stream>>>(qb, kb, vt, pO, pM, pL);
        attn_merge_kernel<<<dim3(32, 4), 256, 0, stream>>>(pO, pM, pL, out);
    } else {
        attn_kernel<<<BATCH * (CTX / 16), 64, 0, stream>>>(qb, kb, vt, out);
    }
}